// Round 1
// baseline (1886.171 us; speedup 1.0000x reference)
//
#include <hip/hip_runtime.h>
#include <math.h>

typedef unsigned int uint;
typedef unsigned short ushort;

#define HID   4096
#define N3    12288
#define NH    32
#define HD    128
#define SEQ   2048
#define BATCH 2
#define MROWS 4096   // B*S

typedef __attribute__((ext_vector_type(4))) float  f32x4;
typedef __attribute__((ext_vector_type(8))) short  bf16x8;
typedef __attribute__((ext_vector_type(4))) ushort u16x4;

static __device__ __forceinline__ ushort f2bf(float f) {
    uint u = __builtin_bit_cast(uint, f);
    u += 0x7fffu + ((u >> 16) & 1u);       // RNE (finite inputs only)
    return (ushort)(u >> 16);
}
static __device__ __forceinline__ float bf2f(ushort s) {
    uint u = ((uint)s) << 16;
    return __builtin_bit_cast(float, u);
}
static __device__ __forceinline__ uint pack2(float a, float b) {
    return (uint)f2bf(a) | ((uint)f2bf(b) << 16);
}

// ---------------------------------------------------------------------------
// GEMM: C[M,N] = A[M,K] * B[K,N], A f32 or bf16, B f32 (converted), C f32/bf16
// 128x128 tile, BK=32, 4 waves (2x2), mfma_f32_16x16x32_bf16.
// A_lds: [128][40] row-major (k contiguous).  B staged TRANSPOSED:
// elem (k,n) -> Blds[n*40 + ((k>>3)^((n>>3)&3))*8 + (k&7)]  (16B-block XOR swizzle)
// ---------------------------------------------------------------------------
template<int A_BF16, int OUT_BF16>
__global__ __launch_bounds__(256) void gemm_kernel(
    const void* __restrict__ Ap, const float* __restrict__ Bw,
    void* __restrict__ Cp, int K, int lda, int ldb, int ldc)
{
    __shared__ __align__(16) ushort Alds[128 * 40];
    __shared__ __align__(16) ushort Blds[128 * 40];

    const int tid = threadIdx.x;
    const int w = tid >> 6, l = tid & 63, c = l & 15, G = l >> 4;
    const int wr = w >> 1, wc = w & 1;
    const int m0 = blockIdx.y * 128, n0 = blockIdx.x * 128;

    f32x4 acc[4][4];
#pragma unroll
    for (int mi = 0; mi < 4; ++mi)
#pragma unroll
        for (int ni = 0; ni < 4; ++ni)
            acc[mi][ni] = (f32x4){0.f, 0.f, 0.f, 0.f};

    for (int k0 = 0; k0 < K; k0 += 32) {
        // ---- stage A tile 128x32 ----
#pragma unroll
        for (int i = 0; i < 2; ++i) {
            int seg = i * 256 + tid;
            int m = seg >> 2, kk = (seg & 3) * 8;
            if (A_BF16) {
                const ushort* ap = (const ushort*)Ap + (size_t)(m0 + m) * lda + k0 + kk;
                *(uint4*)&Alds[m * 40 + kk] = *(const uint4*)ap;
            } else {
                const float* ap = (const float*)Ap + (size_t)(m0 + m) * lda + k0 + kk;
                float4 f0 = *(const float4*)ap;
                float4 f1 = *(const float4*)(ap + 4);
                uint4 v;
                v.x = pack2(f0.x, f0.y); v.y = pack2(f0.z, f0.w);
                v.z = pack2(f1.x, f1.y); v.w = pack2(f1.z, f1.w);
                *(uint4*)&Alds[m * 40 + kk] = v;
            }
        }
        // ---- stage B tile 32x128 transposed+swizzled ----
#pragma unroll
        for (int i = 0; i < 2; ++i) {
            int seg = i * 256 + tid;
            int kk = seg >> 4, nn = (seg & 15) * 8;
            const float* bp = Bw + (size_t)(k0 + kk) * ldb + n0 + nn;
            float4 f0 = *(const float4*)bp;
            float4 f1 = *(const float4*)(bp + 4);
            int ebase = (((kk >> 3) ^ ((nn >> 3) & 3)) << 3) + (kk & 7);
            Blds[(nn + 0) * 40 + ebase] = f2bf(f0.x);
            Blds[(nn + 1) * 40 + ebase] = f2bf(f0.y);
            Blds[(nn + 2) * 40 + ebase] = f2bf(f0.z);
            Blds[(nn + 3) * 40 + ebase] = f2bf(f0.w);
            Blds[(nn + 4) * 40 + ebase] = f2bf(f1.x);
            Blds[(nn + 5) * 40 + ebase] = f2bf(f1.y);
            Blds[(nn + 6) * 40 + ebase] = f2bf(f1.z);
            Blds[(nn + 7) * 40 + ebase] = f2bf(f1.w);
        }
        __syncthreads();

        bf16x8 af[4], bf[4];
#pragma unroll
        for (int mi = 0; mi < 4; ++mi)
            af[mi] = *(const bf16x8*)&Alds[(wr * 64 + mi * 16 + c) * 40 + 8 * G];
#pragma unroll
        for (int ni = 0; ni < 4; ++ni) {
            int n = wc * 64 + ni * 16 + c;
            int blk = G ^ ((n >> 3) & 3);
            bf[ni] = *(const bf16x8*)&Blds[n * 40 + blk * 8];
        }
#pragma unroll
        for (int mi = 0; mi < 4; ++mi)
#pragma unroll
            for (int ni = 0; ni < 4; ++ni)
                acc[mi][ni] = __builtin_amdgcn_mfma_f32_16x16x32_bf16(
                    af[mi], bf[ni], acc[mi][ni], 0, 0, 0);
        __syncthreads();
    }

    // ---- epilogue ----
#pragma unroll
    for (int mi = 0; mi < 4; ++mi)
#pragma unroll
        for (int ni = 0; ni < 4; ++ni) {
            int row = m0 + wr * 64 + mi * 16 + 4 * G;
            int col = n0 + wc * 64 + ni * 16 + c;
#pragma unroll
            for (int r_ = 0; r_ < 4; ++r_) {
                if (OUT_BF16)
                    ((ushort*)Cp)[(size_t)(row + r_) * ldc + col] = f2bf(acc[mi][ni][r_]);
                else
                    ((float*)Cp)[(size_t)(row + r_) * ldc + col] = acc[mi][ni][r_];
            }
        }
}

// ---------------------------------------------------------------------------
// RoPE in-place on bf16 qkv buffer (q and k sections). One thread per (row,
// q/k, head, d<64) pair; pairs d with d+64.
// ---------------------------------------------------------------------------
__global__ __launch_bounds__(256) void rope_kernel(ushort* qkv, const int* __restrict__ pos)
{
    int tid = blockIdx.x * 256 + threadIdx.x;
    int d  = tid & 63;
    int h  = (tid >> 6) & 31;
    int qk = (tid >> 11) & 1;
    int r  = tid >> 12;
    float p = (float)pos[r];
    // 10000^(-d/64) = 2^(-d*log2(10000)/64)
    float inv = exp2f(-0.20762050593296276f * (float)d);
    float ang = p * inv;
    float sn, cs;
    sincosf(ang, &sn, &cs);
    ushort* base = qkv + (size_t)r * N3 + qk * HID + h * HD + d;
    float x1 = bf2f(base[0]);
    float x2 = bf2f(base[64]);
    base[0]  = f2bf(x1 * cs - x2 * sn);
    base[64] = f2bf(x2 * cs + x1 * sn);
}

// ---------------------------------------------------------------------------
// Causal flash attention. Block = 4 waves; Q tile 64 rows (16/wave), KV tile 64.
// K_lds row-major [64][136] (pad kills b128 bank conflicts).
// V transposed into [d=128][kv 72] with 16B-block XOR swizzle (aligned b128).
// Scores via mfma(Q, K^T); online softmax with scaling folded into exp2;
// P -> per-wave LDS -> A-operand fragments; PV via mfma(P, V).
// Output overwrites the Q section of qkv (race-free, see analysis).
// ---------------------------------------------------------------------------
__global__ __launch_bounds__(256) void attn_kernel(ushort* qkv)
{
    __shared__ __align__(16) ushort Klds[64 * 136];
    __shared__ __align__(16) ushort Vt[128 * 72];
    __shared__ __align__(16) ushort Plds[4 * 16 * 72];

    const int qt = blockIdx.x, h = blockIdx.y, b = blockIdx.z;
    const int tid = threadIdx.x;
    const int w = tid >> 6, l = tid & 63, c = l & 15, G = l >> 4;
    const float SC2 = 0.08838834764831845f * 1.4426950408889634f; // scale*log2(e)

    const ushort* Qp = qkv + (size_t)(b * SEQ + qt * 64 + w * 16 + c) * N3 + h * HD;
    bf16x8 qf[4];
#pragma unroll
    for (int kc = 0; kc < 4; ++kc)
        qf[kc] = *(const bf16x8*)(Qp + kc * 32 + 8 * G);

    f32x4 o[8];
#pragma unroll
    for (int nd = 0; nd < 8; ++nd) o[nd] = (f32x4){0.f, 0.f, 0.f, 0.f};
    float mrun[4] = {-INFINITY, -INFINITY, -INFINITY, -INFINITY};
    float lrun[4] = {0.f, 0.f, 0.f, 0.f};

    const ushort* Kbase = qkv + (size_t)b * SEQ * N3 + HID + h * HD;
    const ushort* Vbase = qkv + (size_t)b * SEQ * N3 + 2 * HID + h * HD;

    for (int t = 0; t <= qt; ++t) {
        int kv0 = t * 64;
        // ---- stage K tile [64][128] ----
#pragma unroll
        for (int i = 0; i < 4; ++i) {
            int seg = i * 256 + tid;
            int r = seg >> 4, c0 = (seg & 15) * 8;
            uint4 kvv = *(const uint4*)(Kbase + (size_t)(kv0 + r) * N3 + c0);
            *(uint4*)&Klds[r * 136 + c0] = kvv;
        }
        // ---- stage V transposed [d][kv] swizzled ----
        {
            int r0 = (tid >> 4) * 4;
            int c0 = (tid & 15) * 8;
            union { uint4 v; ushort s[8]; } va, vb, vc, vd;
            va.v = *(const uint4*)(Vbase + (size_t)(kv0 + r0 + 0) * N3 + c0);
            vb.v = *(const uint4*)(Vbase + (size_t)(kv0 + r0 + 1) * N3 + c0);
            vc.v = *(const uint4*)(Vbase + (size_t)(kv0 + r0 + 2) * N3 + c0);
            vd.v = *(const uint4*)(Vbase + (size_t)(kv0 + r0 + 3) * N3 + c0);
#pragma unroll
            for (int j = 0; j < 8; ++j) {
                int d = c0 + j;
                int blk = (r0 >> 3) ^ ((d >> 3) & 7);
                u16x4 pk = {va.s[j], vb.s[j], vc.s[j], vd.s[j]};
                *(u16x4*)&Vt[d * 72 + blk * 8 + (r0 & 7)] = pk;
            }
        }
        __syncthreads();

        // ---- scores = Q * K^T ----
        f32x4 sc[4];
#pragma unroll
        for (int nf = 0; nf < 4; ++nf) sc[nf] = (f32x4){0.f, 0.f, 0.f, 0.f};
#pragma unroll
        for (int nf = 0; nf < 4; ++nf)
#pragma unroll
            for (int kc = 0; kc < 4; ++kc) {
                bf16x8 kf = *(const bf16x8*)&Klds[(16 * nf + c) * 136 + 32 * kc + 8 * G];
                sc[nf] = __builtin_amdgcn_mfma_f32_16x16x32_bf16(qf[kc], kf, sc[nf], 0, 0, 0);
            }

        // ---- causal mask (only the diagonal tile) ----
        if (t == qt) {
#pragma unroll
            for (int nf = 0; nf < 4; ++nf)
#pragma unroll
                for (int r_ = 0; r_ < 4; ++r_)
                    if (16 * nf + c > w * 16 + 4 * G + r_)
                        sc[nf][r_] = -INFINITY;
        }

        // ---- online softmax ----
        float alpha[4];
        float p[4][4];
#pragma unroll
        for (int r_ = 0; r_ < 4; ++r_) {
            float pm = fmaxf(fmaxf(sc[0][r_], sc[1][r_]), fmaxf(sc[2][r_], sc[3][r_]));
#pragma unroll
            for (int msk = 1; msk < 16; msk <<= 1)
                pm = fmaxf(pm, __shfl_xor(pm, msk, 64));
            float mnew = fmaxf(mrun[r_], pm);
            float al = exp2f((mrun[r_] - mnew) * SC2);
            float rs = 0.f;
#pragma unroll
            for (int nf = 0; nf < 4; ++nf) {
                float pv = exp2f((sc[nf][r_] - mnew) * SC2);
                pv = bf2f(f2bf(pv));   // match stored precision in the sum
                p[nf][r_] = pv;
                rs += pv;
            }
#pragma unroll
            for (int msk = 1; msk < 16; msk <<= 1)
                rs += __shfl_xor(rs, msk, 64);
            lrun[r_] = lrun[r_] * al + rs;
            mrun[r_] = mnew;
            alpha[r_] = al;
        }
#pragma unroll
        for (int nd = 0; nd < 8; ++nd)
#pragma unroll
            for (int r_ = 0; r_ < 4; ++r_)
                o[nd][r_] *= alpha[r_];

        // ---- P to per-wave LDS (D-layout -> A-layout round trip) ----
#pragma unroll
        for (int nf = 0; nf < 4; ++nf)
#pragma unroll
            for (int r_ = 0; r_ < 4; ++r_)
                Plds[w * 1152 + (4 * G + r_) * 72 + 16 * nf + c] = f2bf(p[nf][r_]);

        // ---- PV ----
#pragma unroll
        for (int kc2 = 0; kc2 < 2; ++kc2) {
            bf16x8 pa = *(const bf16x8*)&Plds[w * 1152 + c * 72 + 32 * kc2 + 8 * G];
#pragma unroll
            for (int nd = 0; nd < 8; ++nd) {
                int dn = 16 * nd + c;
                int blk = (4 * kc2 + G) ^ ((dn >> 3) & 7);
                bf16x8 vb = *(const bf16x8*)&Vt[dn * 72 + blk * 8];
                o[nd] = __builtin_amdgcn_mfma_f32_16x16x32_bf16(pa, vb, o[nd], 0, 0, 0);
            }
        }
        __syncthreads();
    }

    // ---- epilogue: write into Q section ----
    float inv[4];
#pragma unroll
    for (int r_ = 0; r_ < 4; ++r_) inv[r_] = 1.0f / lrun[r_];
    ushort* Op = qkv + (size_t)(b * SEQ + qt * 64 + w * 16) * N3 + h * HD;
#pragma unroll
    for (int nd = 0; nd < 8; ++nd)
#pragma unroll
        for (int r_ = 0; r_ < 4; ++r_)
            Op[(size_t)(4 * G + r_) * N3 + 16 * nd + c] = f2bf(o[nd][r_] * inv[r_]);
}

// ---------------------------------------------------------------------------
extern "C" void kernel_launch(void* const* d_in, const int* in_sizes, int n_in,
                              void* d_out, int out_size, void* d_ws, size_t ws_size,
                              hipStream_t stream)
{
    const int*   positions = (const int*)d_in[0];
    const float* hidden    = (const float*)d_in[1];
    const float* Wqkv      = (const float*)d_in[2];
    const float* Wo        = (const float*)d_in[3];
    ushort* qkv = (ushort*)d_ws;   // [4096][12288] bf16 = 100.7 MB

    dim3 blk(256);
    // 1) qkv = hidden @ W_qkv  (f32 in, bf16 out)
    gemm_kernel<0, 1><<<dim3(N3 / 128, MROWS / 128), blk, 0, stream>>>(
        hidden, Wqkv, qkv, HID, HID, N3, N3);
    // 2) RoPE in place on q,k
    rope_kernel<<<dim3((MROWS * 2 * NH * 64) / 256), blk, 0, stream>>>(qkv, positions);
    // 3) attention; output overwrites Q section of qkv
    attn_kernel<<<dim3(SEQ / 64, NH, BATCH), blk, 0, stream>>>(qkv);
    // 4) out = attn @ W_o  (bf16 A from ws, f32 out)
    gemm_kernel<1, 0><<<dim3(HID / 128, MROWS / 128), blk, 0, stream>>>(
        qkv, Wo, (float*)d_out, HID, N3, HID, HID);
    (void)in_sizes; (void)n_in; (void)out_size; (void)ws_size;
}

// Round 2
// 1591.119 us; speedup vs baseline: 1.1854x; 1.1854x over previous
//
#include <hip/hip_runtime.h>
#include <math.h>

typedef unsigned int uint;
typedef unsigned short ushort;

#define HID   4096
#define N3    12288
#define NH    32
#define HD    128
#define SEQ   2048
#define BATCH 2
#define MROWS 4096   // B*S

typedef __attribute__((ext_vector_type(4))) float  f32x4;
typedef __attribute__((ext_vector_type(8))) short  bf16x8;
typedef __attribute__((ext_vector_type(4))) ushort u16x4;

static __device__ __forceinline__ ushort f2bf(float f) {
    uint u = __builtin_bit_cast(uint, f);
    u += 0x7fffu + ((u >> 16) & 1u);       // RNE (finite inputs only)
    return (ushort)(u >> 16);
}
static __device__ __forceinline__ float bf2f(ushort s) {
    uint u = ((uint)s) << 16;
    return __builtin_bit_cast(float, u);
}
static __device__ __forceinline__ uint pack2(float a, float b) {
    return (uint)f2bf(a) | ((uint)f2bf(b) << 16);
}
static __device__ __forceinline__ void gld_lds16(const ushort* g, ushort* l) {
    __builtin_amdgcn_global_load_lds(
        (const __attribute__((address_space(1))) void*)g,
        (__attribute__((address_space(3))) void*)l, 16, 0, 0);
}

// ---------------------------------------------------------------------------
// f32 -> bf16 elementwise (8 elems/thread)
// ---------------------------------------------------------------------------
__global__ __launch_bounds__(256) void conv_f32_bf16(
    const float* __restrict__ src, ushort* __restrict__ dst)
{
    size_t i = ((size_t)blockIdx.x * 256 + threadIdx.x) * 8;
    float4 f0 = *(const float4*)&src[i];
    float4 f1 = *(const float4*)&src[i + 4];
    uint4 v;
    v.x = pack2(f0.x, f0.y); v.y = pack2(f0.z, f0.w);
    v.z = pack2(f1.x, f1.y); v.w = pack2(f1.z, f1.w);
    *(uint4*)&dst[i] = v;
}

// ---------------------------------------------------------------------------
// W[K][N] f32  ->  Wt[N][K] bf16   (64x64 LDS tile transpose)
// ---------------------------------------------------------------------------
__global__ __launch_bounds__(256) void transpose_conv(
    const float* __restrict__ W, ushort* __restrict__ Wt, int Ncols, int Krows)
{
    __shared__ float T[64][65];
    const int n0 = blockIdx.x * 64, k0 = blockIdx.y * 64;
    const int tc = (threadIdx.x & 15) * 4, tr = threadIdx.x >> 4;
#pragma unroll
    for (int i = 0; i < 4; ++i) {
        float4 v = *(const float4*)&W[(size_t)(k0 + tr + i * 16) * Ncols + n0 + tc];
        T[tr + i * 16][tc + 0] = v.x; T[tr + i * 16][tc + 1] = v.y;
        T[tr + i * 16][tc + 2] = v.z; T[tr + i * 16][tc + 3] = v.w;
    }
    __syncthreads();
    const int on = threadIdx.x >> 2;          // 0..63 output row (n)
    const int ok = (threadIdx.x & 3) * 16;    // k chunk
    ushort tmp[16];
#pragma unroll
    for (int j = 0; j < 16; ++j) tmp[j] = f2bf(T[ok + j][on]);
    ushort* out = Wt + (size_t)(n0 + on) * Krows + k0 + ok;
    *(uint4*)out       = *(uint4*)&tmp[0];
    *(uint4*)(out + 8) = *(uint4*)&tmp[8];
}

// ---------------------------------------------------------------------------
// GEMM (m97 structure): C[M][N] = A[M][K] * Bt[N][K]^T, all bf16 in, f32 acc.
// 128x128 tile, BK=64, 4 waves (2x2), global_load_lds width 16, linear LDS.
// ---------------------------------------------------------------------------
template<int OUT_BF16>
__global__ __launch_bounds__(256) void gemm_tn(
    const ushort* __restrict__ A, const ushort* __restrict__ Bt,
    void* __restrict__ Cp, int K, int lda, int ldb, int ldc)
{
    __shared__ __align__(16) ushort Alds[128 * 64];
    __shared__ __align__(16) ushort Blds[128 * 64];

    const int tid = threadIdx.x;
    const int w = tid >> 6, l = tid & 63, c = l & 15, G = l >> 4;
    const int wr = w >> 1, wc = w & 1;
    const int m0 = blockIdx.y * 128, n0 = blockIdx.x * 128;

    f32x4 acc[4][4];
#pragma unroll
    for (int mi = 0; mi < 4; ++mi)
#pragma unroll
        for (int ni = 0; ni < 4; ++ni)
            acc[mi][ni] = (f32x4){0.f, 0.f, 0.f, 0.f};

    // staging geometry: wave w stages rows [w*32, w*32+32); lane l covers
    // row w*32 + i*8 + (l>>3), elems (l&7)*8 .. +8  -> LDS linear lane*16B
    const int srow = w * 32 + (l >> 3);
    const int selem = (l & 7) * 8;
    const ushort* Ag = A + (size_t)(m0 + srow) * lda + selem;
    const ushort* Bg = Bt + (size_t)(n0 + srow) * ldb + selem;
    ushort* Al = &Alds[(w * 32) * 64];
    ushort* Bl = &Blds[(w * 32) * 64];

    for (int k0 = 0; k0 < K; k0 += 64) {
#pragma unroll
        for (int i = 0; i < 4; ++i)
            gld_lds16(Ag + k0 + (size_t)i * 8 * lda, Al + i * 8 * 64);
#pragma unroll
        for (int i = 0; i < 4; ++i)
            gld_lds16(Bg + k0 + (size_t)i * 8 * ldb, Bl + i * 8 * 64);
        __syncthreads();

        bf16x8 af[2][4], bfr[2][4];
#pragma unroll
        for (int kk = 0; kk < 2; ++kk) {
#pragma unroll
            for (int mi = 0; mi < 4; ++mi)
                af[kk][mi] = *(const bf16x8*)&Alds[(wr * 64 + mi * 16 + c) * 64 + kk * 32 + 8 * G];
#pragma unroll
            for (int ni = 0; ni < 4; ++ni)
                bfr[kk][ni] = *(const bf16x8*)&Blds[(wc * 64 + ni * 16 + c) * 64 + kk * 32 + 8 * G];
        }
#pragma unroll
        for (int kk = 0; kk < 2; ++kk)
#pragma unroll
            for (int mi = 0; mi < 4; ++mi)
#pragma unroll
                for (int ni = 0; ni < 4; ++ni)
                    acc[mi][ni] = __builtin_amdgcn_mfma_f32_16x16x32_bf16(
                        af[kk][mi], bfr[kk][ni], acc[mi][ni], 0, 0, 0);
        __syncthreads();
    }

#pragma unroll
    for (int mi = 0; mi < 4; ++mi)
#pragma unroll
        for (int ni = 0; ni < 4; ++ni) {
            int row = m0 + wr * 64 + mi * 16 + 4 * G;
            int col = n0 + wc * 64 + ni * 16 + c;
#pragma unroll
            for (int r_ = 0; r_ < 4; ++r_) {
                if (OUT_BF16)
                    ((ushort*)Cp)[(size_t)(row + r_) * ldc + col] = f2bf(acc[mi][ni][r_]);
                else
                    ((float*)Cp)[(size_t)(row + r_) * ldc + col] = acc[mi][ni][r_];
            }
        }
}

// ---------------------------------------------------------------------------
// RoPE in-place on bf16 qkv buffer (q and k sections).
// ---------------------------------------------------------------------------
__global__ __launch_bounds__(256) void rope_kernel(ushort* qkv, const int* __restrict__ pos)
{
    int tid = blockIdx.x * 256 + threadIdx.x;
    int d  = tid & 63;
    int h  = (tid >> 6) & 31;
    int qk = (tid >> 11) & 1;
    int r  = tid >> 12;
    float p = (float)pos[r];
    float inv = exp2f(-0.20762050593296276f * (float)d);  // 10000^(-d/64)
    float ang = p * inv;
    float sn, cs;
    sincosf(ang, &sn, &cs);
    ushort* base = qkv + (size_t)r * N3 + qk * HID + h * HD + d;
    float x1 = bf2f(base[0]);
    float x2 = bf2f(base[64]);
    base[0]  = f2bf(x1 * cs - x2 * sn);
    base[64] = f2bf(x2 * cs + x1 * sn);
}

// ---------------------------------------------------------------------------
// Causal flash attention (unchanged from round 0; known-correct).
// ---------------------------------------------------------------------------
__global__ __launch_bounds__(256) void attn_kernel(ushort* qkv)
{
    __shared__ __align__(16) ushort Klds[64 * 136];
    __shared__ __align__(16) ushort Vt[128 * 72];
    __shared__ __align__(16) ushort Plds[4 * 16 * 72];

    const int qt = blockIdx.x, h = blockIdx.y, b = blockIdx.z;
    const int tid = threadIdx.x;
    const int w = tid >> 6, l = tid & 63, c = l & 15, G = l >> 4;
    const float SC2 = 0.08838834764831845f * 1.4426950408889634f; // scale*log2(e)

    const ushort* Qp = qkv + (size_t)(b * SEQ + qt * 64 + w * 16 + c) * N3 + h * HD;
    bf16x8 qf[4];
#pragma unroll
    for (int kc = 0; kc < 4; ++kc)
        qf[kc] = *(const bf16x8*)(Qp + kc * 32 + 8 * G);

    f32x4 o[8];
#pragma unroll
    for (int nd = 0; nd < 8; ++nd) o[nd] = (f32x4){0.f, 0.f, 0.f, 0.f};
    float mrun[4] = {-INFINITY, -INFINITY, -INFINITY, -INFINITY};
    float lrun[4] = {0.f, 0.f, 0.f, 0.f};

    const ushort* Kbase = qkv + (size_t)b * SEQ * N3 + HID + h * HD;
    const ushort* Vbase = qkv + (size_t)b * SEQ * N3 + 2 * HID + h * HD;

    for (int t = 0; t <= qt; ++t) {
        int kv0 = t * 64;
#pragma unroll
        for (int i = 0; i < 4; ++i) {
            int seg = i * 256 + tid;
            int r = seg >> 4, c0 = (seg & 15) * 8;
            uint4 kvv = *(const uint4*)(Kbase + (size_t)(kv0 + r) * N3 + c0);
            *(uint4*)&Klds[r * 136 + c0] = kvv;
        }
        {
            int r0 = (tid >> 4) * 4;
            int c0 = (tid & 15) * 8;
            union { uint4 v; ushort s[8]; } va, vb, vc, vd;
            va.v = *(const uint4*)(Vbase + (size_t)(kv0 + r0 + 0) * N3 + c0);
            vb.v = *(const uint4*)(Vbase + (size_t)(kv0 + r0 + 1) * N3 + c0);
            vc.v = *(const uint4*)(Vbase + (size_t)(kv0 + r0 + 2) * N3 + c0);
            vd.v = *(const uint4*)(Vbase + (size_t)(kv0 + r0 + 3) * N3 + c0);
#pragma unroll
            for (int j = 0; j < 8; ++j) {
                int d = c0 + j;
                int blk = (r0 >> 3) ^ ((d >> 3) & 7);
                u16x4 pk = {va.s[j], vb.s[j], vc.s[j], vd.s[j]};
                *(u16x4*)&Vt[d * 72 + blk * 8 + (r0 & 7)] = pk;
            }
        }
        __syncthreads();

        f32x4 sc[4];
#pragma unroll
        for (int nf = 0; nf < 4; ++nf) sc[nf] = (f32x4){0.f, 0.f, 0.f, 0.f};
#pragma unroll
        for (int nf = 0; nf < 4; ++nf)
#pragma unroll
            for (int kc = 0; kc < 4; ++kc) {
                bf16x8 kf = *(const bf16x8*)&Klds[(16 * nf + c) * 136 + 32 * kc + 8 * G];
                sc[nf] = __builtin_amdgcn_mfma_f32_16x16x32_bf16(qf[kc], kf, sc[nf], 0, 0, 0);
            }

        if (t == qt) {
#pragma unroll
            for (int nf = 0; nf < 4; ++nf)
#pragma unroll
                for (int r_ = 0; r_ < 4; ++r_)
                    if (16 * nf + c > w * 16 + 4 * G + r_)
                        sc[nf][r_] = -INFINITY;
        }

        float alpha[4];
        float p[4][4];
#pragma unroll
        for (int r_ = 0; r_ < 4; ++r_) {
            float pm = fmaxf(fmaxf(sc[0][r_], sc[1][r_]), fmaxf(sc[2][r_], sc[3][r_]));
#pragma unroll
            for (int msk = 1; msk < 16; msk <<= 1)
                pm = fmaxf(pm, __shfl_xor(pm, msk, 64));
            float mnew = fmaxf(mrun[r_], pm);
            float al = exp2f((mrun[r_] - mnew) * SC2);
            float rs = 0.f;
#pragma unroll
            for (int nf = 0; nf < 4; ++nf) {
                float pv = exp2f((sc[nf][r_] - mnew) * SC2);
                pv = bf2f(f2bf(pv));
                p[nf][r_] = pv;
                rs += pv;
            }
#pragma unroll
            for (int msk = 1; msk < 16; msk <<= 1)
                rs += __shfl_xor(rs, msk, 64);
            lrun[r_] = lrun[r_] * al + rs;
            mrun[r_] = mnew;
            alpha[r_] = al;
        }
#pragma unroll
        for (int nd = 0; nd < 8; ++nd)
#pragma unroll
            for (int r_ = 0; r_ < 4; ++r_)
                o[nd][r_] *= alpha[r_];

#pragma unroll
        for (int nf = 0; nf < 4; ++nf)
#pragma unroll
            for (int r_ = 0; r_ < 4; ++r_)
                Plds[w * 1152 + (4 * G + r_) * 72 + 16 * nf + c] = f2bf(p[nf][r_]);

#pragma unroll
        for (int kc2 = 0; kc2 < 2; ++kc2) {
            bf16x8 pa = *(const bf16x8*)&Plds[w * 1152 + c * 72 + 32 * kc2 + 8 * G];
#pragma unroll
            for (int nd = 0; nd < 8; ++nd) {
                int dn = 16 * nd + c;
                int blk = (4 * kc2 + G) ^ ((dn >> 3) & 7);
                bf16x8 vb = *(const bf16x8*)&Vt[dn * 72 + blk * 8];
                o[nd] = __builtin_amdgcn_mfma_f32_16x16x32_bf16(pa, vb, o[nd], 0, 0, 0);
            }
        }
        __syncthreads();
    }

    float inv[4];
#pragma unroll
    for (int r_ = 0; r_ < 4; ++r_) inv[r_] = 1.0f / lrun[r_];
    ushort* Op = qkv + (size_t)(b * SEQ + qt * 64 + w * 16) * N3 + h * HD;
#pragma unroll
    for (int nd = 0; nd < 8; ++nd)
#pragma unroll
        for (int r_ = 0; r_ < 4; ++r_)
            Op[(size_t)(4 * G + r_) * N3 + 16 * nd + c] = f2bf(o[nd][r_] * inv[r_]);
}

// ---------------------------------------------------------------------------
extern "C" void kernel_launch(void* const* d_in, const int* in_sizes, int n_in,
                              void* d_out, int out_size, void* d_ws, size_t ws_size,
                              hipStream_t stream)
{
    const int*   positions = (const int*)d_in[0];
    const float* hidden    = (const float*)d_in[1];
    const float* Wqkv      = (const float*)d_in[2];
    const float* Wo        = (const float*)d_in[3];

    // workspace layout (bytes):
    //   qkv : [4096][12288] bf16 = 100,663,296
    //   Abf : [4096][4096]  bf16 =  33,554,432
    //   Wt  : up to [12288][4096] bf16 = 100,663,296 (Wqkv_t, later reused Wo_t)
    ushort* qkv = (ushort*)d_ws;
    ushort* Abf = (ushort*)((char*)d_ws + 100663296);
    ushort* Wt  = (ushort*)((char*)d_ws + 134217728);

    dim3 blk(256);
    // 0a) hidden -> bf16
    conv_f32_bf16<<<dim3((MROWS * HID) / (8 * 256)), blk, 0, stream>>>(hidden, Abf);
    // 0b) W_qkv [4096][12288] -> Wt [12288][4096] bf16
    transpose_conv<<<dim3(N3 / 64, HID / 64), blk, 0, stream>>>(Wqkv, Wt, N3, HID);
    // 1) qkv = Abf @ Wt^T  (bf16 out)
    gemm_tn<1><<<dim3(N3 / 128, MROWS / 128), blk, 0, stream>>>(
        Abf, Wt, qkv, HID, HID, HID, N3);
    // 2) RoPE in place on q,k
    rope_kernel<<<dim3((MROWS * 2 * NH * 64) / 256), blk, 0, stream>>>(qkv, positions);
    // 3) attention; output overwrites Q section of qkv
    attn_kernel<<<dim3(SEQ / 64, NH, BATCH), blk, 0, stream>>>(qkv);
    // 0c) W_o [4096][4096] -> Wt [4096][4096] bf16 (reuse region; stream-ordered)
    transpose_conv<<<dim3(HID / 64, HID / 64), blk, 0, stream>>>(Wo, Wt, HID, HID);
    // 4) out = attn @ Wt^T  (f32 out)
    gemm_tn<0><<<dim3(HID / 128, MROWS / 128), blk, 0, stream>>>(
        qkv, Wt, (float*)d_out, HID, N3, HID, HID);
    (void)positions; (void)in_sizes; (void)n_in; (void)out_size; (void)ws_size;
}

// Round 3
// 1543.863 us; speedup vs baseline: 1.2217x; 1.0306x over previous
//
#include <hip/hip_runtime.h>
#include <math.h>

typedef unsigned int uint;
typedef unsigned short ushort;

#define HID   4096
#define N3    12288
#define NH    32
#define HD    128
#define SEQ   2048
#define BATCH 2
#define MROWS 4096   // B*S

typedef __attribute__((ext_vector_type(4))) float  f32x4;
typedef __attribute__((ext_vector_type(8))) short  bf16x8;
typedef __attribute__((ext_vector_type(4))) ushort u16x4;

static __device__ __forceinline__ ushort f2bf(float f) {
    uint u = __builtin_bit_cast(uint, f);
    u += 0x7fffu + ((u >> 16) & 1u);       // RNE (finite inputs only)
    return (ushort)(u >> 16);
}
static __device__ __forceinline__ float bf2f(ushort s) {
    uint u = ((uint)s) << 16;
    return __builtin_bit_cast(float, u);
}
static __device__ __forceinline__ uint pack2(float a, float b) {
    return (uint)f2bf(a) | ((uint)f2bf(b) << 16);
}
static __device__ __forceinline__ void gld_lds16(const ushort* g, ushort* l) {
    __builtin_amdgcn_global_load_lds(
        (const __attribute__((address_space(1))) void*)g,
        (__attribute__((address_space(3))) void*)l, 16, 0, 0);
}

// ---------------------------------------------------------------------------
// f32 -> bf16 elementwise (8 elems/thread)
// ---------------------------------------------------------------------------
__global__ __launch_bounds__(256) void conv_f32_bf16(
    const float* __restrict__ src, ushort* __restrict__ dst)
{
    size_t i = ((size_t)blockIdx.x * 256 + threadIdx.x) * 8;
    float4 f0 = *(const float4*)&src[i];
    float4 f1 = *(const float4*)&src[i + 4];
    uint4 v;
    v.x = pack2(f0.x, f0.y); v.y = pack2(f0.z, f0.w);
    v.z = pack2(f1.x, f1.y); v.w = pack2(f1.z, f1.w);
    *(uint4*)&dst[i] = v;
}

// ---------------------------------------------------------------------------
// W[K][N] f32  ->  Wt[N][K] bf16   (64x64 LDS tile transpose)
// ---------------------------------------------------------------------------
__global__ __launch_bounds__(256) void transpose_conv(
    const float* __restrict__ W, ushort* __restrict__ Wt, int Ncols, int Krows)
{
    __shared__ float T[64][65];
    const int n0 = blockIdx.x * 64, k0 = blockIdx.y * 64;
    const int tc = (threadIdx.x & 15) * 4, tr = threadIdx.x >> 4;
#pragma unroll
    for (int i = 0; i < 4; ++i) {
        float4 v = *(const float4*)&W[(size_t)(k0 + tr + i * 16) * Ncols + n0 + tc];
        T[tr + i * 16][tc + 0] = v.x; T[tr + i * 16][tc + 1] = v.y;
        T[tr + i * 16][tc + 2] = v.z; T[tr + i * 16][tc + 3] = v.w;
    }
    __syncthreads();
    const int on = threadIdx.x >> 2;          // 0..63 output row (n)
    const int ok = (threadIdx.x & 3) * 16;    // k chunk
    ushort tmp[16];
#pragma unroll
    for (int j = 0; j < 16; ++j) tmp[j] = f2bf(T[ok + j][on]);
    ushort* out = Wt + (size_t)(n0 + on) * Krows + k0 + ok;
    *(uint4*)out       = *(uint4*)&tmp[0];
    *(uint4*)(out + 8) = *(uint4*)&tmp[8];
}

// ---------------------------------------------------------------------------
// GEMM (exact m97 structure): C[M][N] = A[M][K] * Bt[N][K]^T, bf16 in, f32 acc.
// 128x128 tile, BK=32 (16 KB LDS), 4 waves (2x2), global_load_lds width 16.
// LDS [128][32] linear; 64 B rows -> 8-way conflict on fragment reads
// (m97-proven acceptable at this structure; T2 swizzle is NULL at 128^2/2ph).
// ---------------------------------------------------------------------------
template<int OUT_BF16>
__global__ __launch_bounds__(256) void gemm_tn(
    const ushort* __restrict__ A, const ushort* __restrict__ Bt,
    void* __restrict__ Cp, int K, int lda, int ldb, int ldc)
{
    __shared__ __align__(16) ushort Alds[128 * 32];
    __shared__ __align__(16) ushort Blds[128 * 32];

    const int tid = threadIdx.x;
    const int w = tid >> 6, l = tid & 63, c = l & 15, G = l >> 4;
    const int wr = w >> 1, wc = w & 1;
    const int m0 = blockIdx.y * 128, n0 = blockIdx.x * 128;

    f32x4 acc[4][4];
#pragma unroll
    for (int mi = 0; mi < 4; ++mi)
#pragma unroll
        for (int ni = 0; ni < 4; ++ni)
            acc[mi][ni] = (f32x4){0.f, 0.f, 0.f, 0.f};

    // staging: per K-step, inst i in {0,1}: row = i*64 + w*16 + (l>>2),
    // elems (l&3)*8 .. +8.  LDS linear: bytes w*1024 + l*16 (+ i*4096).
    const int srow = w * 16 + (l >> 2);
    const int sel  = (l & 3) * 8;
    const ushort* Ag = A + (size_t)(m0 + srow) * lda + sel;
    const ushort* Bg = Bt + (size_t)(n0 + srow) * ldb + sel;
    ushort* Al = Alds + w * 512;   // elements (1024 B)
    ushort* Bl = Blds + w * 512;

    for (int k0 = 0; k0 < K; k0 += 32) {
        gld_lds16(Ag + k0, Al);
        gld_lds16(Ag + k0 + (size_t)64 * lda, Al + 2048);
        gld_lds16(Bg + k0, Bl);
        gld_lds16(Bg + k0 + (size_t)64 * ldb, Bl + 2048);
        __syncthreads();

        bf16x8 af[4], bfr[4];
#pragma unroll
        for (int mi = 0; mi < 4; ++mi)
            af[mi] = *(const bf16x8*)&Alds[(wr * 64 + mi * 16 + c) * 32 + 8 * G];
#pragma unroll
        for (int ni = 0; ni < 4; ++ni)
            bfr[ni] = *(const bf16x8*)&Blds[(wc * 64 + ni * 16 + c) * 32 + 8 * G];
#pragma unroll
        for (int mi = 0; mi < 4; ++mi)
#pragma unroll
            for (int ni = 0; ni < 4; ++ni)
                acc[mi][ni] = __builtin_amdgcn_mfma_f32_16x16x32_bf16(
                    af[mi], bfr[ni], acc[mi][ni], 0, 0, 0);
        __syncthreads();
    }

#pragma unroll
    for (int mi = 0; mi < 4; ++mi)
#pragma unroll
        for (int ni = 0; ni < 4; ++ni) {
            int row = m0 + wr * 64 + mi * 16 + 4 * G;
            int col = n0 + wc * 64 + ni * 16 + c;
#pragma unroll
            for (int r_ = 0; r_ < 4; ++r_) {
                if (OUT_BF16)
                    ((ushort*)Cp)[(size_t)(row + r_) * ldc + col] = f2bf(acc[mi][ni][r_]);
                else
                    ((float*)Cp)[(size_t)(row + r_) * ldc + col] = acc[mi][ni][r_];
            }
        }
}

// ---------------------------------------------------------------------------
// RoPE in-place on bf16 qkv buffer (q and k sections).
// ---------------------------------------------------------------------------
__global__ __launch_bounds__(256) void rope_kernel(ushort* qkv, const int* __restrict__ pos)
{
    int tid = blockIdx.x * 256 + threadIdx.x;
    int d  = tid & 63;
    int h  = (tid >> 6) & 31;
    int qk = (tid >> 11) & 1;
    int r  = tid >> 12;
    float p = (float)pos[r];
    float inv = exp2f(-0.20762050593296276f * (float)d);  // 10000^(-d/64)
    float ang = p * inv;
    float sn, cs;
    sincosf(ang, &sn, &cs);
    ushort* base = qkv + (size_t)r * N3 + qk * HID + h * HD + d;
    float x1 = bf2f(base[0]);
    float x2 = bf2f(base[64]);
    base[0]  = f2bf(x1 * cs - x2 * sn);
    base[64] = f2bf(x2 * cs + x1 * sn);
}

// ---------------------------------------------------------------------------
// Causal flash attention (unchanged; known-correct).
// ---------------------------------------------------------------------------
__global__ __launch_bounds__(256) void attn_kernel(ushort* qkv)
{
    __shared__ __align__(16) ushort Klds[64 * 136];
    __shared__ __align__(16) ushort Vt[128 * 72];
    __shared__ __align__(16) ushort Plds[4 * 16 * 72];

    const int qt = blockIdx.x, h = blockIdx.y, b = blockIdx.z;
    const int tid = threadIdx.x;
    const int w = tid >> 6, l = tid & 63, c = l & 15, G = l >> 4;
    const float SC2 = 0.08838834764831845f * 1.4426950408889634f; // scale*log2(e)

    const ushort* Qp = qkv + (size_t)(b * SEQ + qt * 64 + w * 16 + c) * N3 + h * HD;
    bf16x8 qf[4];
#pragma unroll
    for (int kc = 0; kc < 4; ++kc)
        qf[kc] = *(const bf16x8*)(Qp + kc * 32 + 8 * G);

    f32x4 o[8];
#pragma unroll
    for (int nd = 0; nd < 8; ++nd) o[nd] = (f32x4){0.f, 0.f, 0.f, 0.f};
    float mrun[4] = {-INFINITY, -INFINITY, -INFINITY, -INFINITY};
    float lrun[4] = {0.f, 0.f, 0.f, 0.f};

    const ushort* Kbase = qkv + (size_t)b * SEQ * N3 + HID + h * HD;
    const ushort* Vbase = qkv + (size_t)b * SEQ * N3 + 2 * HID + h * HD;

    for (int t = 0; t <= qt; ++t) {
        int kv0 = t * 64;
#pragma unroll
        for (int i = 0; i < 4; ++i) {
            int seg = i * 256 + tid;
            int r = seg >> 4, c0 = (seg & 15) * 8;
            uint4 kvv = *(const uint4*)(Kbase + (size_t)(kv0 + r) * N3 + c0);
            *(uint4*)&Klds[r * 136 + c0] = kvv;
        }
        {
            int r0 = (tid >> 4) * 4;
            int c0 = (tid & 15) * 8;
            union { uint4 v; ushort s[8]; } va, vb, vc, vd;
            va.v = *(const uint4*)(Vbase + (size_t)(kv0 + r0 + 0) * N3 + c0);
            vb.v = *(const uint4*)(Vbase + (size_t)(kv0 + r0 + 1) * N3 + c0);
            vc.v = *(const uint4*)(Vbase + (size_t)(kv0 + r0 + 2) * N3 + c0);
            vd.v = *(const uint4*)(Vbase + (size_t)(kv0 + r0 + 3) * N3 + c0);
#pragma unroll
            for (int j = 0; j < 8; ++j) {
                int d = c0 + j;
                int blk = (r0 >> 3) ^ ((d >> 3) & 7);
                u16x4 pk = {va.s[j], vb.s[j], vc.s[j], vd.s[j]};
                *(u16x4*)&Vt[d * 72 + blk * 8 + (r0 & 7)] = pk;
            }
        }
        __syncthreads();

        f32x4 sc[4];
#pragma unroll
        for (int nf = 0; nf < 4; ++nf) sc[nf] = (f32x4){0.f, 0.f, 0.f, 0.f};
#pragma unroll
        for (int nf = 0; nf < 4; ++nf)
#pragma unroll
            for (int kc = 0; kc < 4; ++kc) {
                bf16x8 kf = *(const bf16x8*)&Klds[(16 * nf + c) * 136 + 32 * kc + 8 * G];
                sc[nf] = __builtin_amdgcn_mfma_f32_16x16x32_bf16(qf[kc], kf, sc[nf], 0, 0, 0);
            }

        if (t == qt) {
#pragma unroll
            for (int nf = 0; nf < 4; ++nf)
#pragma unroll
                for (int r_ = 0; r_ < 4; ++r_)
                    if (16 * nf + c > w * 16 + 4 * G + r_)
                        sc[nf][r_] = -INFINITY;
        }

        float alpha[4];
        float p[4][4];
#pragma unroll
        for (int r_ = 0; r_ < 4; ++r_) {
            float pm = fmaxf(fmaxf(sc[0][r_], sc[1][r_]), fmaxf(sc[2][r_], sc[3][r_]));
#pragma unroll
            for (int msk = 1; msk < 16; msk <<= 1)
                pm = fmaxf(pm, __shfl_xor(pm, msk, 64));
            float mnew = fmaxf(mrun[r_], pm);
            float al = exp2f((mrun[r_] - mnew) * SC2);
            float rs = 0.f;
#pragma unroll
            for (int nf = 0; nf < 4; ++nf) {
                float pv = exp2f((sc[nf][r_] - mnew) * SC2);
                pv = bf2f(f2bf(pv));
                p[nf][r_] = pv;
                rs += pv;
            }
#pragma unroll
            for (int msk = 1; msk < 16; msk <<= 1)
                rs += __shfl_xor(rs, msk, 64);
            lrun[r_] = lrun[r_] * al + rs;
            mrun[r_] = mnew;
            alpha[r_] = al;
        }
#pragma unroll
        for (int nd = 0; nd < 8; ++nd)
#pragma unroll
            for (int r_ = 0; r_ < 4; ++r_)
                o[nd][r_] *= alpha[r_];

#pragma unroll
        for (int nf = 0; nf < 4; ++nf)
#pragma unroll
            for (int r_ = 0; r_ < 4; ++r_)
                Plds[w * 1152 + (4 * G + r_) * 72 + 16 * nf + c] = f2bf(p[nf][r_]);

#pragma unroll
        for (int kc2 = 0; kc2 < 2; ++kc2) {
            bf16x8 pa = *(const bf16x8*)&Plds[w * 1152 + c * 72 + 32 * kc2 + 8 * G];
#pragma unroll
            for (int nd = 0; nd < 8; ++nd) {
                int dn = 16 * nd + c;
                int blk = (4 * kc2 + G) ^ ((dn >> 3) & 7);
                bf16x8 vb = *(const bf16x8*)&Vt[dn * 72 + blk * 8];
                o[nd] = __builtin_amdgcn_mfma_f32_16x16x32_bf16(pa, vb, o[nd], 0, 0, 0);
            }
        }
        __syncthreads();
    }

    float inv[4];
#pragma unroll
    for (int r_ = 0; r_ < 4; ++r_) inv[r_] = 1.0f / lrun[r_];
    ushort* Op = qkv + (size_t)(b * SEQ + qt * 64 + w * 16) * N3 + h * HD;
#pragma unroll
    for (int nd = 0; nd < 8; ++nd)
#pragma unroll
        for (int r_ = 0; r_ < 4; ++r_)
            Op[(size_t)(4 * G + r_) * N3 + 16 * nd + c] = f2bf(o[nd][r_] * inv[r_]);
}

// ---------------------------------------------------------------------------
extern "C" void kernel_launch(void* const* d_in, const int* in_sizes, int n_in,
                              void* d_out, int out_size, void* d_ws, size_t ws_size,
                              hipStream_t stream)
{
    const int*   positions = (const int*)d_in[0];
    const float* hidden    = (const float*)d_in[1];
    const float* Wqkv      = (const float*)d_in[2];
    const float* Wo        = (const float*)d_in[3];

    // workspace layout (bytes):
    //   qkv : [4096][12288] bf16 = 100,663,296
    //   Abf : [4096][4096]  bf16 =  33,554,432
    //   Wt  : up to [12288][4096] bf16 = 100,663,296 (Wqkv_t, later reused Wo_t)
    ushort* qkv = (ushort*)d_ws;
    ushort* Abf = (ushort*)((char*)d_ws + 100663296);
    ushort* Wt  = (ushort*)((char*)d_ws + 134217728);

    dim3 blk(256);
    // 0a) hidden -> bf16
    conv_f32_bf16<<<dim3((MROWS * HID) / (8 * 256)), blk, 0, stream>>>(hidden, Abf);
    // 0b) W_qkv [4096][12288] -> Wt [12288][4096] bf16
    transpose_conv<<<dim3(N3 / 64, HID / 64), blk, 0, stream>>>(Wqkv, Wt, N3, HID);
    // 1) qkv = Abf @ Wt^T  (bf16 out)
    gemm_tn<1><<<dim3(N3 / 128, MROWS / 128), blk, 0, stream>>>(
        Abf, Wt, qkv, HID, HID, HID, N3);
    // 2) RoPE in place on q,k
    rope_kernel<<<dim3((MROWS * 2 * NH * 64) / 256), blk, 0, stream>>>(qkv, positions);
    // 3) attention; output overwrites Q section of qkv
    attn_kernel<<<dim3(SEQ / 64, NH, BATCH), blk, 0, stream>>>(qkv);
    // 0c) W_o [4096][4096] -> Wt [4096][4096] bf16 (reuse region; stream-ordered)
    transpose_conv<<<dim3(HID / 64, HID / 64), blk, 0, stream>>>(Wo, Wt, HID, HID);
    // 4) out = attn @ Wt^T  (f32 out)
    gemm_tn<0><<<dim3(HID / 128, MROWS / 128), blk, 0, stream>>>(
        qkv, Wt, (float*)d_out, HID, N3, HID, HID);
    (void)positions; (void)in_sizes; (void)n_in; (void)out_size; (void)ws_size;
}